// Round 5
// baseline (390.912 us; speedup 1.0000x reference)
//
#include <hip/hip_runtime.h>

// TreeLSTM cell: one bf16-MFMA GEMM [131072,512]x[512,1024] + gated epilogue.
// v5: 256-thr blocks (4 waves, 2M x 2N), 128 rows x (4seg x 64 hcol of group g).
// LDS = 64KB exactly -> 2 independent blocks/CU (cross-block port/MFMA overlap).
//   A: dbuf 2 x 16KB (128r x 64k), depth-2 stage.  B: two K-half buffers 2 x 16KB
//   (h0 = k[0,32), h1 = k[32,64) of the current kt), each staged depth-1 with >= 1/2-kt lead.
// Counted vmcnt (hand-enumerated, never 0 mid-loop), 4 phases/kt {6 ds_read -> 8 MFMA},
// setprio around MFMA, child_c gather prefetched to registers in the prologue.

typedef unsigned short u16;
typedef unsigned int u32;
typedef __bf16 bf16x8 __attribute__((ext_vector_type(8)));
typedef float f32x16 __attribute__((ext_vector_type(16)));
typedef u16 u16x4 __attribute__((ext_vector_type(4)));
typedef u16 u16x8 __attribute__((ext_vector_type(8)));

#define NTOT 131072
#define NHOFF ((size_t)131072 * 256)
#define AS1 __attribute__((address_space(1)))
#define AS3 __attribute__((address_space(3)))

__device__ __forceinline__ u16 f2bf(float f) {
  u32 u = __float_as_uint(f);
  return (u16)((u + 0x7FFFu + ((u >> 16) & 1u)) >> 16);  // RNE
}

// ---- v5 B layout: [g][kt(8)][h(2)][1024 slots of 16B] ----
// slot s: pcol r = s>>2 (64B rows of 32 k), c16 = s&3, stored chunk = c16 ^ (r&3)
// (XOR swizzle pre-applied so in-kernel staging is a fully linear copy).
__global__ void prep_w_v5(const float* __restrict__ Wiou, const float* __restrict__ Uiou,
                          const float* __restrict__ Wf, const float* __restrict__ Uf,
                          u16* __restrict__ Bpack) {
  int cid = blockIdx.x * 256 + threadIdx.x;   // 65536 slots
  int s = cid & 1023;
  int h = (cid >> 10) & 1;
  int kt = (cid >> 11) & 7;
  int g = cid >> 14;
  int r = s >> 2, c16 = s & 3;
  int chunk = c16 ^ (r & 3);
  int seg = r >> 6, e = r & 63;
  int j = seg * 256 + g * 64 + e;             // pre-col in [0,1024)
  int k0 = kt * 64 + h * 32 + chunk * 8;      // k in [0,512)
  const float* src;
  if (j < 768) src = (k0 < 256) ? (Wiou + (size_t)j * 256 + k0) : (Uiou + (size_t)j * 256 + (k0 - 256));
  else { int jj = j - 768; src = (k0 < 256) ? (Wf + (size_t)jj * 256 + k0) : (Uf + (size_t)jj * 256 + (k0 - 256)); }
  float4 f0 = *(const float4*)(src);
  float4 f1 = *(const float4*)(src + 4);
  u16x8 v;
  v[0] = f2bf(f0.x); v[1] = f2bf(f0.y); v[2] = f2bf(f0.z); v[3] = f2bf(f0.w);
  v[4] = f2bf(f1.x); v[5] = f2bf(f1.y); v[6] = f2bf(f1.z); v[7] = f2bf(f1.w);
  *(u16x8*)(Bpack + (size_t)cid * 8) = v;
}

// ---- legacy B layout (fallback path only) ----
__global__ void prep_w_legacy(const float* __restrict__ Wiou, const float* __restrict__ Uiou,
                              const float* __restrict__ Wf, const float* __restrict__ Uf,
                              u16* __restrict__ Bpack) {
  int cid = blockIdx.x * 256 + threadIdx.x;
  int j = cid >> 6;
  int kc = cid & 63;
  int k = kc * 8;
  int kt = kc >> 3, k8 = kc & 7;
  int s = j >> 8, g = (j >> 6) & 3, e = j & 63;
  int c = s * 64 + e;
  const float* src;
  if (j < 768) src = (k < 256) ? (Wiou + j * 256 + k) : (Uiou + j * 256 + (k - 256));
  else { int jj = j - 768; src = (k < 256) ? (Wf + jj * 256 + k) : (Uf + jj * 256 + (k - 256)); }
  float4 f0 = *(const float4*)(src);
  float4 f1 = *(const float4*)(src + 4);
  u16x8 v;
  v[0] = f2bf(f0.x); v[1] = f2bf(f0.y); v[2] = f2bf(f0.z); v[3] = f2bf(f0.w);
  v[4] = f2bf(f1.x); v[5] = f2bf(f1.y); v[6] = f2bf(f1.z); v[7] = f2bf(f1.w);
  int slot = (g * 8 + kt) * 2048 + ((c * 8 + k8) ^ (c & 7));
  *(u16x8*)(Bpack + slot * 8) = v;
}

__global__ void prep_bias(const float* __restrict__ biou, const float* __restrict__ wfb,
                          const float* __restrict__ ufb, const float* __restrict__ bfv,
                          float* __restrict__ Bias) {
  int j = blockIdx.x * 256 + threadIdx.x;  // 1024 exact
  Bias[j] = (j < 768) ? biou[j] : (wfb[j - 768] + ufb[j - 768] + bfv[j - 768]);
}

// Apack[n] = [ x[n] (512B bf16) | child_h[idx[n]] (512B bf16) ], row-major.
__global__ void prep_apack(const float* __restrict__ x, const float* __restrict__ ch,
                           const int* __restrict__ cidx, u16* __restrict__ Apack) {
  int e = blockIdx.x * 256 + threadIdx.x;  // 131072 rows x 64 chunks of 8
  int n = e >> 6, c = e & 63;
  const float* src = (c < 32) ? (x + (size_t)n * 256 + c * 8)
                              : (ch + (size_t)cidx[n] * 256 + (c - 32) * 8);
  float4 f0 = *(const float4*)src;
  float4 f1 = *(const float4*)(src + 4);
  u16x8 v;
  v[0] = f2bf(f0.x); v[1] = f2bf(f0.y); v[2] = f2bf(f0.z); v[3] = f2bf(f0.w);
  v[4] = f2bf(f1.x); v[5] = f2bf(f1.y); v[6] = f2bf(f1.z); v[7] = f2bf(f1.w);
  *(u16x8*)(Apack + (size_t)n * 512 + c * 8) = v;
}

// -------------------- v5 main --------------------
__global__ __launch_bounds__(256, 2)
void treelstm_main_v5(const u16* __restrict__ Apack, const u16* __restrict__ Bpack,
                      const float* __restrict__ Bias, const float* __restrict__ child_c,
                      const int* __restrict__ cidx, float* __restrict__ out) {
  // Bytes: A0 [0,16K), A1 [16K,32K), Bh0 [32K,48K), Bh1 [48K,64K)
  __shared__ __align__(16) u16 lds[32768];   // 64 KB exactly -> 2 blocks/CU
  char* ldsByte = (char*)lds;

  const int tid = threadIdx.x;
  // XCD-chunked bijective swizzle (4096 % 8 == 0); g-inner so the 4 sibling g-blocks
  // sharing one A row-tile are adjacent on the same XCD (L2 reuse).
  const int orig = blockIdx.x;
  const int bid = (orig & 7) * 512 + (orig >> 3);
  const int g = bid & 3;
  const int n0 = (bid >> 2) * 128;

  const int lane = tid & 63, w = tid >> 6;
  const int wm = w >> 1, wn = w & 1;   // wave tile: 64 rows x (4 segs x 32 hcols)
  const int lr = lane & 31, hi = lane >> 5;
  const int hcol = g * 64 + wn * 32 + lr;

  // ---- prologue: prefetch cidx -> child_c into registers (oldest in vmcnt order) ----
  int ci[2][16];
  #pragma unroll
  for (int mi = 0; mi < 2; ++mi)
    #pragma unroll
    for (int r = 0; r < 16; ++r)
      ci[mi][r] = cidx[n0 + wm * 64 + mi * 32 + (r & 3) + 8 * (r >> 2) + 4 * hi];
  float ccv[2][16];
  #pragma unroll
  for (int mi = 0; mi < 2; ++mi)
    #pragma unroll
    for (int r = 0; r < 16; ++r)
      ccv[mi][r] = *(volatile const float*)(child_c + (size_t)ci[mi][r] * 256 + hcol);
  __builtin_amdgcn_sched_barrier(0);

  // A staging source: per-lane, inverse-swizzled (rule #21); LDS dest linear.
  // slot s = q*256+tid -> row r = q*32+(tid>>3), src chunk = (tid&7)^((tid>>3)&7).
  const u16* aSrc = Apack + (size_t)(n0 + (tid >> 3)) * 512
                    + (((tid & 7) ^ ((tid >> 3) & 7)) << 3);
  // B staging source: pre-swizzled image, fully linear.
  const u16* bSrc = Bpack + (size_t)g * 131072 + (size_t)tid * 8;

  int arowB[2];
  #pragma unroll
  for (int mi = 0; mi < 2; mi++) arowB[mi] = (wm * 64 + mi * 32 + lr) * 128;  // 128B rows
  int browB[4];
  #pragma unroll
  for (int s4 = 0; s4 < 4; s4++) browB[s4] = (s4 * 64 + wn * 32 + lr) * 64;   // 64B rows
  int aoff[4], boff[2];
  #pragma unroll
  for (int ks = 0; ks < 4; ++ks) aoff[ks] = (ks * 32 + hi * 16) ^ ((lr & 7) << 4);
  #pragma unroll
  for (int k1 = 0; k1 < 2; ++k1) boff[k1] = (k1 * 32 + hi * 16) ^ ((lr & 3) << 4);

  f32x16 acc[2][4] = {};   // [mi][seg]

  #define STAGE_A(T)                                                            \
    { _Pragma("unroll") for (int q = 0; q < 4; ++q)                             \
        __builtin_amdgcn_global_load_lds(                                       \
            (const AS1 void*)(aSrc + (T) * 64 + q * 16384),                     \
            (AS3 void*)(ldsByte + ((T) & 1) * 16384 + q * 4096 + w * 1024),     \
            16, 0, 0); }
  #define STAGE_B(T, H)                                                         \
    { _Pragma("unroll") for (int q = 0; q < 4; ++q)                             \
        __builtin_amdgcn_global_load_lds(                                       \
            (const AS1 void*)(bSrc + (T) * 16384 + (H) * 8192 + q * 2048),      \
            (AS3 void*)(ldsByte + 32768 + (H) * 16384 + q * 4096 + w * 1024),   \
            16, 0, 0); }

  // Prologue stages. vmcnt issue order: [ccv.., A0(4), B0h0(4), B0h1(4), A1(4)]
  STAGE_A(0);
  STAGE_B(0, 0);
  STAGE_B(0, 1);
  STAGE_A(1);

  #define PHASE(T, KS)                                                          \
    { const char* bA_ = ldsByte + ((T) & 1) * 16384;                            \
      const char* bB_ = ldsByte + 32768 + ((KS) >> 1) * 16384;                  \
      bf16x8 af_[2], bf_[4];                                                    \
      _Pragma("unroll") for (int mi = 0; mi < 2; ++mi)                          \
        af_[mi] = *(const bf16x8*)(bA_ + arowB[mi] + aoff[(KS)]);               \
      _Pragma("unroll") for (int nf = 0; nf < 4; ++nf)                          \
        bf_[nf] = *(const bf16x8*)(bB_ + browB[nf] + boff[(KS) & 1]);           \
      __builtin_amdgcn_s_setprio(1);                                            \
      _Pragma("unroll") for (int mi = 0; mi < 2; ++mi)                          \
        _Pragma("unroll") for (int nf = 0; nf < 4; ++nf)                        \
          acc[mi][nf] = __builtin_amdgcn_mfma_f32_32x32x16_bf16(                \
              af_[mi], bf_[nf], acc[mi][nf], 0, 0, 0);                          \
      __builtin_amdgcn_s_setprio(0); }

  // vmcnt enumeration (4 loads per STAGE_A / STAGE_B-half):
  //  t top outstanding -> wait:  t=0: [ccv,A0,B0h0,B0h1 | A1] -> 4
  //  t in 1..6: [A(t),B(t)h0 | B(t)h1,A(t+1)] -> 8;  t=7: [A7,B7h0 | B7h1] -> 4
  //  mid-t: want B(t)h1 done -> leave A(t+1): 4 (t<7); mid-7 -> 0
  #define KT(T, TWs, MWs)                                                       \
    { asm volatile("s_waitcnt vmcnt(" TWs ")" ::: "memory");                    \
      __builtin_amdgcn_s_barrier();                                             \
      PHASE(T, 0) PHASE(T, 1)                                                   \
      asm volatile("s_waitcnt lgkmcnt(0)" ::: "memory");                        \
      asm volatile("s_waitcnt vmcnt(" MWs ")" ::: "memory");                    \
      __builtin_amdgcn_s_barrier();                                             \
      if ((T) < 7) STAGE_B((T) + 1, 0);                                         \
      PHASE(T, 2) PHASE(T, 3)                                                   \
      asm volatile("s_waitcnt lgkmcnt(0)" ::: "memory");                        \
      __builtin_amdgcn_s_barrier();                                             \
      if ((T) < 7) STAGE_B((T) + 1, 1);                                         \
      if ((T) < 6) STAGE_A((T) + 2); }

  KT(0, "4", "4") KT(1, "8", "4") KT(2, "8", "4") KT(3, "8", "4")
  KT(4, "8", "4") KT(5, "8", "4") KT(6, "8", "4") KT(7, "4", "0")

  #undef KT
  #undef PHASE
  #undef STAGE_A
  #undef STAGE_B

  // ---- epilogue: pure math + stores (ccv already in registers) ----
  float b4[4];
  #pragma unroll
  for (int nf = 0; nf < 4; ++nf) b4[nf] = Bias[nf * 256 + hcol];
  #pragma unroll
  for (int mi = 0; mi < 2; ++mi) {
    #pragma unroll
    for (int reg = 0; reg < 16; ++reg) {
      int rowb = wm * 64 + mi * 32 + (reg & 3) + 8 * (reg >> 2) + 4 * hi;  // C/D map
      size_t n = (size_t)(n0 + rowb);
      float i_ = acc[mi][0][reg] + b4[0];
      float o_ = acc[mi][1][reg] + b4[1];
      float u_ = acc[mi][2][reg] + b4[2];
      float fp = acc[mi][3][reg] + b4[3];
      float sigi = 1.f / (1.f + __expf(-i_));
      float sigo = 1.f / (1.f + __expf(-o_));
      float sigf = 1.f / (1.f + __expf(-fp));
      float tu = 2.f / (1.f + __expf(-2.f * u_)) - 1.f;
      float c = sigi * tu + sigf * ccv[mi][reg];
      float tc = 2.f / (1.f + __expf(-2.f * c)) - 1.f;
      out[n * 256 + hcol] = sigo * tc;
      out[NHOFF + n * 256 + hcol] = c;
    }
  }
}

// ---------- fallback main (round-1 proven path, used if ws too small) ----------
__global__ __launch_bounds__(256, 2)
void treelstm_main_f32(const float* __restrict__ x, const float* __restrict__ child_h,
                       const float* __restrict__ child_c, const int* __restrict__ cidx,
                       const u16* __restrict__ Bpack, const float* __restrict__ Bias,
                       float* __restrict__ out) {
  __shared__ __align__(16) u16 ldsA[128 * 64];
  __shared__ __align__(16) u16 ldsB[256 * 64];
  __shared__ int lds_cidx[128];

  const int tid = threadIdx.x;
  const int n0 = blockIdx.x * 128;
  const int g = blockIdx.y;

  if (tid < 128) lds_cidx[tid] = cidx[n0 + tid];

  const int lane = tid & 63, w = tid >> 6;
  const int wm = w >> 1, wn = w & 1;
  const int lr = lane & 31, hi = lane >> 5;

  f32x16 acc[2][4] = {};

  const char* ldsAb = (const char*)ldsA;
  const char* ldsBb = (const char*)ldsB;
  int arow[2];
  #pragma unroll
  for (int mi = 0; mi < 2; mi++) arow[mi] = (wm * 64 + mi * 32 + lr) * 128;
  const int aswz = (lr & 7) << 4;
  int brow[4];
  #pragma unroll
  for (int s = 0; s < 4; s++) brow[s] = (s * 64 + wn * 32 + lr) * 128;
  const int bswz = (lr & 7) << 4;

  for (int kt = 0; kt < 8; ++kt) {
    #pragma unroll
    for (int q = 0; q < 8; ++q) {
      int v = q * 256 + tid;
      int r = v >> 4;
      int kq = (v & 15) * 4;
      const float* src = (kt < 4) ? (x + (size_t)(n0 + r) * 256 + kt * 64 + kq)
                                  : (child_h + (size_t)lds_cidx[r] * 256 + (kt - 4) * 64 + kq);
      float4 d = *(const float4*)src;
      u16x4 b;
      b[0] = f2bf(d.x); b[1] = f2bf(d.y); b[2] = f2bf(d.z); b[3] = f2bf(d.w);
      int addr = (r * 128 + kq * 2) ^ ((r & 7) << 4);
      *(u16x4*)((char*)ldsA + addr) = b;
    }
    const u16* bsrc = Bpack + (g * 8 + kt) * 16384;
    #pragma unroll
    for (int q = 0; q < 8; ++q) {
      int m = q * 256 + tid;
      *(u16x8*)((char*)ldsB + m * 16) = *(const u16x8*)(bsrc + m * 8);
    }
    __syncthreads();
    #pragma unroll
    for (int ks = 0; ks < 4; ++ks) {
      int kb = ks * 32 + hi * 16;
      bf16x8 af[2], bfr[4];
      #pragma unroll
      for (int mi = 0; mi < 2; mi++)
        af[mi] = *(const bf16x8*)(ldsAb + ((arow[mi] + kb) ^ aswz));
      #pragma unroll
      for (int s = 0; s < 4; s++)
        bfr[s] = *(const bf16x8*)(ldsBb + ((brow[s] + kb) ^ bswz));
      #pragma unroll
      for (int mi = 0; mi < 2; mi++)
        #pragma unroll
        for (int s = 0; s < 4; s++)
          acc[mi][s] = __builtin_amdgcn_mfma_f32_32x32x16_bf16(af[mi], bfr[s], acc[mi][s], 0, 0, 0);
    }
    __syncthreads();
  }

  const int tcol = g * 64 + wn * 32 + lr;
  const float bi = Bias[tcol], bo = Bias[256 + tcol], bu = Bias[512 + tcol], bfg = Bias[768 + tcol];
  #pragma unroll
  for (int mi = 0; mi < 2; mi++) {
    #pragma unroll
    for (int reg = 0; reg < 16; ++reg) {
      int row = wm * 64 + mi * 32 + (reg & 3) + 8 * (reg >> 2) + 4 * hi;
      int n = n0 + row;
      float i_ = acc[mi][0][reg] + bi;
      float o_ = acc[mi][1][reg] + bo;
      float u_ = acc[mi][2][reg] + bu;
      float fp = acc[mi][3][reg] + bfg;
      float ccv = child_c[(size_t)lds_cidx[row] * 256 + tcol];
      float sigi = 1.f / (1.f + __expf(-i_));
      float sigo = 1.f / (1.f + __expf(-o_));
      float sigf = 1.f / (1.f + __expf(-fp));
      float tu = 2.f / (1.f + __expf(-2.f * u_)) - 1.f;
      float c = sigi * tu + sigf * ccv;
      float tc = 2.f / (1.f + __expf(-2.f * c)) - 1.f;
      out[(size_t)n * 256 + tcol] = sigo * tc;
      out[NHOFF + (size_t)n * 256 + tcol] = c;
    }
  }
}

extern "C" void kernel_launch(void* const* d_in, const int* in_sizes, int n_in,
                              void* d_out, int out_size, void* d_ws, size_t ws_size,
                              hipStream_t stream) {
  const float* x    = (const float*)d_in[0];
  const float* ch   = (const float*)d_in[1];
  const float* cc   = (const float*)d_in[2];
  const int*   ci   = (const int*)d_in[3];
  const float* Wiou = (const float*)d_in[4];
  const float* Uiou = (const float*)d_in[5];
  const float* biou = (const float*)d_in[6];
  const float* Wf   = (const float*)d_in[7];
  const float* Wfb  = (const float*)d_in[8];
  const float* Uf   = (const float*)d_in[9];
  const float* Ufb  = (const float*)d_in[10];
  const float* bfv  = (const float*)d_in[11];

  u16* Bpack = (u16*)d_ws;                              // 1 MB bf16 packed weights
  float* Bias = (float*)((char*)d_ws + (1 << 20));      // 4 KB combined bias
  u16* Apack = (u16*)((char*)d_ws + (2 << 20));         // 134.2 MB packed [x|hc] bf16

  const size_t need = (size_t)(2 << 20) + (size_t)NTOT * 512 * sizeof(u16);

  prep_bias<<<4, 256, 0, stream>>>(biou, Wfb, Ufb, bfv, Bias);

  if (ws_size >= need) {
    prep_w_v5<<<256, 256, 0, stream>>>(Wiou, Uiou, Wf, Uf, Bpack);
    prep_apack<<<32768, 256, 0, stream>>>(x, ch, ci, Apack);
    treelstm_main_v5<<<4096, 256, 0, stream>>>(Apack, Bpack, Bias, cc, ci, (float*)d_out);
  } else {
    prep_w_legacy<<<256, 256, 0, stream>>>(Wiou, Uiou, Wf, Uf, Bpack);
    dim3 grid(1024, 4);
    treelstm_main_f32<<<grid, 256, 0, stream>>>(x, ch, cc, ci, Bpack, Bias, (float*)d_out);
  }
}

// Round 6
// 333.463 us; speedup vs baseline: 1.1723x; 1.1723x over previous
//
#include <hip/hip_runtime.h>

// TreeLSTM cell: one bf16-MFMA GEMM [131072,512]x[512,1024] + gated epilogue.
// v7: B never touches LDS. BpackF is fragment-ordered (verified in r3); per kt each
// wave loads its 16 B fragments via coalesced global dwordx4 (L2-resident 1MB).
// A: r2-proven swizzled global_load_lds staging, double-buffered 2x16KB, depth-1
// prefetch, ONE barrier + counted vmcnt(8) per kt (never drains the A prefetch):
//   outstanding at iter-t wait: [STAGE_A(t) 4? no: STAGE_A(t+0) retired; see below]
//   issue order per iter: b0(t) 8 loads | wait vmcnt(8)+bar | STAGE_A(t+1) 4 |
//   ds_read A 8 | b1(t) 8 loads | MFMA. At the wait, own outstanding =
//   [STAGE_A(t) 4 (from prev iter), b0(t) 8] -> vmcnt(8) == STAGE_A(t) landed.
// 4 waves/block (2M x 2N), wave tile 64 rows x (4seg x 32 hcol); i,o,u,f lane-local.

typedef unsigned short u16;
typedef unsigned int u32;
typedef __bf16 bf16x8 __attribute__((ext_vector_type(8)));
typedef float f32x16 __attribute__((ext_vector_type(16)));
typedef u16 u16x4 __attribute__((ext_vector_type(4)));
typedef u16 u16x8 __attribute__((ext_vector_type(8)));

#define NTOT 131072
#define NHOFF ((size_t)131072 * 256)
#define AS1 __attribute__((address_space(1)))
#define AS3 __attribute__((address_space(3)))

__device__ __forceinline__ u16 f2bf(float f) {
  u32 u = __float_as_uint(f);
  return (u16)((u + 0x7FFFu + ((u >> 16) & 1u)) >> 16);  // RNE
}

// ---- B in fragment order (verified r3): [g(4)][kt(8)][ks(4)][hi(2)][np(256)][8 bf16]
// np = nf*64 + wn*32 + lr  ->  pre-col j = nf*256 + g*64 + wn*32 + lr  (seg nf).
__global__ void prep_w_frag(const float* __restrict__ Wiou, const float* __restrict__ Uiou,
                            const float* __restrict__ Wf, const float* __restrict__ Uf,
                            u16* __restrict__ BpackF) {
  int c = blockIdx.x * 256 + threadIdx.x;  // 65536 chunks of 8 k-elems
  int np = c & 255;
  int r = c >> 8;
  int hi = r & 1; r >>= 1;
  int ks = r & 3; r >>= 2;
  int kt = r & 7; r >>= 3;
  int g  = r & 3;
  int j = (np >> 6) * 256 + g * 64 + (np & 63);
  int k0 = kt * 64 + ks * 16 + hi * 8;
  const float* src;
  if (j < 768) src = (k0 < 256) ? (Wiou + (size_t)j * 256 + k0) : (Uiou + (size_t)j * 256 + (k0 - 256));
  else { int jj = j - 768; src = (k0 < 256) ? (Wf + (size_t)jj * 256 + k0) : (Uf + (size_t)jj * 256 + (k0 - 256)); }
  float4 f0 = *(const float4*)(src);
  float4 f1 = *(const float4*)(src + 4);
  u16x8 v;
  v[0] = f2bf(f0.x); v[1] = f2bf(f0.y); v[2] = f2bf(f0.z); v[3] = f2bf(f0.w);
  v[4] = f2bf(f1.x); v[5] = f2bf(f1.y); v[6] = f2bf(f1.z); v[7] = f2bf(f1.w);
  *(u16x8*)(BpackF + (size_t)c * 8) = v;
}

// ---- legacy B layout (fallback path only) ----
__global__ void prep_w_legacy(const float* __restrict__ Wiou, const float* __restrict__ Uiou,
                              const float* __restrict__ Wf, const float* __restrict__ Uf,
                              u16* __restrict__ Bpack) {
  int cid = blockIdx.x * 256 + threadIdx.x;
  int j = cid >> 6;
  int kc = cid & 63;
  int k = kc * 8;
  int kt = kc >> 3, k8 = kc & 7;
  int s = j >> 8, g = (j >> 6) & 3, e = j & 63;
  int c = s * 64 + e;
  const float* src;
  if (j < 768) src = (k < 256) ? (Wiou + j * 256 + k) : (Uiou + j * 256 + (k - 256));
  else { int jj = j - 768; src = (k < 256) ? (Wf + jj * 256 + k) : (Uf + jj * 256 + (k - 256)); }
  float4 f0 = *(const float4*)(src);
  float4 f1 = *(const float4*)(src + 4);
  u16x8 v;
  v[0] = f2bf(f0.x); v[1] = f2bf(f0.y); v[2] = f2bf(f0.z); v[3] = f2bf(f0.w);
  v[4] = f2bf(f1.x); v[5] = f2bf(f1.y); v[6] = f2bf(f1.z); v[7] = f2bf(f1.w);
  int slot = (g * 8 + kt) * 2048 + ((c * 8 + k8) ^ (c & 7));
  *(u16x8*)(Bpack + slot * 8) = v;
}

__global__ void prep_bias(const float* __restrict__ biou, const float* __restrict__ wfb,
                          const float* __restrict__ ufb, const float* __restrict__ bfv,
                          float* __restrict__ Bias) {
  int j = blockIdx.x * 256 + threadIdx.x;  // 1024 exact
  Bias[j] = (j < 768) ? biou[j] : (wfb[j - 768] + ufb[j - 768] + bfv[j - 768]);
}

// Apack[n] = [ x[n] (512B bf16) | child_h[idx[n]] (512B bf16) ], row-major.
__global__ void prep_apack(const float* __restrict__ x, const float* __restrict__ ch,
                           const int* __restrict__ cidx, u16* __restrict__ Apack) {
  int e = blockIdx.x * 256 + threadIdx.x;  // 131072 rows x 64 chunks of 8
  int n = e >> 6, c = e & 63;
  const float* src = (c < 32) ? (x + (size_t)n * 256 + c * 8)
                              : (ch + (size_t)cidx[n] * 256 + (c - 32) * 8);
  float4 f0 = *(const float4*)src;
  float4 f1 = *(const float4*)(src + 4);
  u16x8 v;
  v[0] = f2bf(f0.x); v[1] = f2bf(f0.y); v[2] = f2bf(f0.z); v[3] = f2bf(f0.w);
  v[4] = f2bf(f1.x); v[5] = f2bf(f1.y); v[6] = f2bf(f1.z); v[7] = f2bf(f1.w);
  *(u16x8*)(Apack + (size_t)n * 512 + c * 8) = v;
}

// -------------------- v7 main: A via LDS dbuf, B direct to registers --------------------
__global__ __launch_bounds__(256, 2)
void treelstm_main_v7(const u16* __restrict__ Apack, const u16* __restrict__ BpackF,
                      const float* __restrict__ Bias, const float* __restrict__ child_c,
                      const int* __restrict__ cidx, float* __restrict__ out) {
  __shared__ __align__(16) u16 ldsA[2 * 8192];   // 2 x 16KB A tiles (128 rows x 64 k)
  __shared__ int lds_cidx[128];
  char* ldsByte = (char*)ldsA;

  const int tid = threadIdx.x;
  // XCD-chunked bijective swizzle (4096 % 8 == 0); g-inner: 4 sibling g-blocks of one
  // A row-tile adjacent on the same XCD (A + child_c L2 reuse).
  const int orig = blockIdx.x;
  const int bid = (orig & 7) * 512 + (orig >> 3);
  const int g = bid & 3;
  const int n0 = (bid >> 2) * 128;

  if (tid < 128) lds_cidx[tid] = cidx[n0 + tid];   // visible after iter-0 barrier

  const int lane = tid & 63, w = tid >> 6;
  const int wm = w >> 1, wn = w & 1;   // wave tile: 64 rows x (4 segs x 32 hcols)
  const int lr = lane & 31, hi = lane >> 5;

  // A staging source: per-lane, inverse-swizzled (rule #21); LDS dest linear.
  const u16* aSrc = Apack + (size_t)(n0 + (tid >> 3)) * 512
                    + (((tid & 7) ^ ((tid >> 3) & 7)) << 3);
  // B fragment base: lanes 0-31 read one contiguous 512B block, lanes 32-63 the
  // matching hi=1 block 4KB away -> fully coalesced dwordx4.
  const u16* bP = BpackF + (size_t)g * 131072 + (size_t)hi * 2048 + (size_t)(wn * 32 + lr) * 8;

  int arowB[2];
  #pragma unroll
  for (int mi = 0; mi < 2; mi++) arowB[mi] = (wm * 64 + mi * 32 + lr) * 128;  // 128B rows
  int aoff[4];
  #pragma unroll
  for (int ks = 0; ks < 4; ++ks) aoff[ks] = (ks * 32 + hi * 16) ^ ((lr & 7) << 4);

  f32x16 acc[2][4] = {};   // [mi][seg]

  #define STAGE_A(T)                                                            \
    { _Pragma("unroll") for (int q = 0; q < 4; ++q)                             \
        __builtin_amdgcn_global_load_lds(                                       \
            (const AS1 void*)(aSrc + (T) * 64 + q * 16384),                     \
            (AS3 void*)(ldsByte + ((T) & 1) * 16384 + q * 4096 + w * 1024),     \
            16, 0, 0); }

  STAGE_A(0);

  #pragma unroll
  for (int t = 0; t < 8; ++t) {
    // ---- B half0 (ks=0,1): 8 coalesced global loads straight to VGPRs ----
    bf16x8 b0[4][2];
    #pragma unroll
    for (int nf = 0; nf < 4; ++nf)
      #pragma unroll
      for (int kk = 0; kk < 2; ++kk)
        b0[nf][kk] = *(const bf16x8*)(bP + (size_t)t * 16384 + kk * 4096 + nf * 512);
    // ---- A(t) ready gate: own outstanding = [STAGE_A(t) 4, b0 8] -> vmcnt(8) ----
    __builtin_amdgcn_sched_barrier(0);
    asm volatile("s_waitcnt vmcnt(8) lgkmcnt(0)\n\ts_barrier" ::: "memory");
    __builtin_amdgcn_sched_barrier(0);
    if (t < 7) STAGE_A(t + 1);                  // prefetch next tile into other buffer
    // ---- A fragments from LDS (swizzled) ----
    const char* bufA = ldsByte + (t & 1) * 16384;
    bf16x8 af[2][4];
    #pragma unroll
    for (int mi = 0; mi < 2; ++mi)
      #pragma unroll
      for (int ks = 0; ks < 4; ++ks)
        af[mi][ks] = *(const bf16x8*)(bufA + arowB[mi] + aoff[ks]);
    // ---- B half1 (ks=2,3) issued before MFMA half0 so L2 latency hides under it ----
    bf16x8 b1[4][2];
    #pragma unroll
    for (int nf = 0; nf < 4; ++nf)
      #pragma unroll
      for (int kk = 0; kk < 2; ++kk)
        b1[nf][kk] = *(const bf16x8*)(bP + (size_t)t * 16384 + (kk + 2) * 4096 + nf * 512);
    // ---- MFMA half0 ----
    __builtin_amdgcn_s_setprio(1);
    #pragma unroll
    for (int kk = 0; kk < 2; ++kk)
      #pragma unroll
      for (int mi = 0; mi < 2; ++mi)
        #pragma unroll
        for (int nf = 0; nf < 4; ++nf)
          acc[mi][nf] = __builtin_amdgcn_mfma_f32_32x32x16_bf16(af[mi][kk], b0[nf][kk],
                                                                acc[mi][nf], 0, 0, 0);
    __builtin_amdgcn_s_setprio(0);
    // ---- MFMA half1 ----
    __builtin_amdgcn_s_setprio(1);
    #pragma unroll
    for (int kk = 0; kk < 2; ++kk)
      #pragma unroll
      for (int mi = 0; mi < 2; ++mi)
        #pragma unroll
        for (int nf = 0; nf < 4; ++nf)
          acc[mi][nf] = __builtin_amdgcn_mfma_f32_32x32x16_bf16(af[mi][kk + 2], b1[nf][kk],
                                                                acc[mi][nf], 0, 0, 0);
    __builtin_amdgcn_s_setprio(0);
  }
  #undef STAGE_A

  // ---- epilogue: i,o,u,f are acc[mi][0..3][reg] in the SAME lane ----
  const int hcol = g * 64 + wn * 32 + lr;
  float b4[4];
  #pragma unroll
  for (int nf = 0; nf < 4; ++nf) b4[nf] = Bias[nf * 256 + hcol];
  #pragma unroll
  for (int mi = 0; mi < 2; ++mi) {
    #pragma unroll
    for (int reg = 0; reg < 16; ++reg) {
      int rowb = wm * 64 + mi * 32 + (reg & 3) + 8 * (reg >> 2) + 4 * hi;  // C/D map
      size_t n = (size_t)(n0 + rowb);
      float i_ = acc[mi][0][reg] + b4[0];
      float o_ = acc[mi][1][reg] + b4[1];
      float u_ = acc[mi][2][reg] + b4[2];
      float fp = acc[mi][3][reg] + b4[3];
      float ccv = child_c[(size_t)lds_cidx[rowb] * 256 + hcol];
      float sigi = 1.f / (1.f + __expf(-i_));
      float sigo = 1.f / (1.f + __expf(-o_));
      float sigf = 1.f / (1.f + __expf(-fp));
      float tu = 2.f / (1.f + __expf(-2.f * u_)) - 1.f;
      float c = sigi * tu + sigf * ccv;
      float tc = 2.f / (1.f + __expf(-2.f * c)) - 1.f;
      out[n * 256 + hcol] = sigo * tc;
      out[NHOFF + n * 256 + hcol] = c;
    }
  }
}

// ---------- fallback main (round-1 proven path, used if ws too small) ----------
__global__ __launch_bounds__(256, 2)
void treelstm_main_f32(const float* __restrict__ x, const float* __restrict__ child_h,
                       const float* __restrict__ child_c, const int* __restrict__ cidx,
                       const u16* __restrict__ Bpack, const float* __restrict__ Bias,
                       float* __restrict__ out) {
  __shared__ __align__(16) u16 ldsA[128 * 64];
  __shared__ __align__(16) u16 ldsB[256 * 64];
  __shared__ int lds_cidx[128];

  const int tid = threadIdx.x;
  const int n0 = blockIdx.x * 128;
  const int g = blockIdx.y;

  if (tid < 128) lds_cidx[tid] = cidx[n0 + tid];

  const int lane = tid & 63, w = tid >> 6;
  const int wm = w >> 1, wn = w & 1;
  const int lr = lane & 31, hi = lane >> 5;

  f32x16 acc[2][4] = {};

  const char* ldsAb = (const char*)ldsA;
  const char* ldsBb = (const char*)ldsB;
  int arow[2];
  #pragma unroll
  for (int mi = 0; mi < 2; mi++) arow[mi] = (wm * 64 + mi * 32 + lr) * 128;
  const int aswz = (lr & 7) << 4;
  int brow[4];
  #pragma unroll
  for (int s = 0; s < 4; s++) brow[s] = (s * 64 + wn * 32 + lr) * 128;
  const int bswz = (lr & 7) << 4;

  for (int kt = 0; kt < 8; ++kt) {
    #pragma unroll
    for (int q = 0; q < 8; ++q) {
      int v = q * 256 + tid;
      int r = v >> 4;
      int kq = (v & 15) * 4;
      const float* src = (kt < 4) ? (x + (size_t)(n0 + r) * 256 + kt * 64 + kq)
                                  : (child_h + (size_t)lds_cidx[r] * 256 + (kt - 4) * 64 + kq);
      float4 d = *(const float4*)src;
      u16x4 b;
      b[0] = f2bf(d.x); b[1] = f2bf(d.y); b[2] = f2bf(d.z); b[3] = f2bf(d.w);
      int addr = (r * 128 + kq * 2) ^ ((r & 7) << 4);
      *(u16x4*)((char*)ldsA + addr) = b;
    }
    const u16* bsrc = Bpack + (g * 8 + kt) * 16384;
    #pragma unroll
    for (int q = 0; q < 8; ++q) {
      int m = q * 256 + tid;
      *(u16x8*)((char*)ldsB + m * 16) = *(const u16x8*)(bsrc + m * 8);
    }
    __syncthreads();
    #pragma unroll
    for (int ks = 0; ks < 4; ++ks) {
      int kb = ks * 32 + hi * 16;
      bf16x8 af[2], bfr[4];
      #pragma unroll
      for (int mi = 0; mi < 2; mi++)
        af[mi] = *(const bf16x8*)(ldsAb + ((arow[mi] + kb) ^ aswz));
      #pragma unroll
      for (int s = 0; s < 4; s++)
        bfr[s] = *(const bf16x8*)(ldsBb + ((brow[s] + kb) ^ bswz));
      #pragma unroll
      for (int mi = 0; mi < 2; mi++)
        #pragma unroll
        for (int s = 0; s < 4; s++)
          acc[mi][s] = __builtin_amdgcn_mfma_f32_32x32x16_bf16(af[mi], bfr[s], acc[mi][s], 0, 0, 0);
    }
    __syncthreads();
  }

  const int tcol = g * 64 + wn * 32 + lr;
  const float bi = Bias[tcol], bo = Bias[256 + tcol], bu = Bias[512 + tcol], bfg = Bias[768 + tcol];
  #pragma unroll
  for (int mi = 0; mi < 2; mi++) {
    #pragma unroll
    for (int reg = 0; reg < 16; ++reg) {
      int row = wm * 64 + mi * 32 + (reg & 3) + 8 * (reg >> 2) + 4 * hi;
      int n = n0 + row;
      float i_ = acc[mi][0][reg] + bi;
      float o_ = acc[mi][1][reg] + bo;
      float u_ = acc[mi][2][reg] + bu;
      float fp = acc[mi][3][reg] + bfg;
      float ccv = child_c[(size_t)lds_cidx[row] * 256 + tcol];
      float sigi = 1.f / (1.f + __expf(-i_));
      float sigo = 1.f / (1.f + __expf(-o_));
      float sigf = 1.f / (1.f + __expf(-fp));
      float tu = 2.f / (1.f + __expf(-2.f * u_)) - 1.f;
      float c = sigi * tu + sigf * ccv;
      float tc = 2.f / (1.f + __expf(-2.f * c)) - 1.f;
      out[(size_t)n * 256 + tcol] = sigo * tc;
      out[NHOFF + (size_t)n * 256 + tcol] = c;
    }
  }
}

extern "C" void kernel_launch(void* const* d_in, const int* in_sizes, int n_in,
                              void* d_out, int out_size, void* d_ws, size_t ws_size,
                              hipStream_t stream) {
  const float* x    = (const float*)d_in[0];
  const float* ch   = (const float*)d_in[1];
  const float* cc   = (const float*)d_in[2];
  const int*   ci   = (const int*)d_in[3];
  const float* Wiou = (const float*)d_in[4];
  const float* Uiou = (const float*)d_in[5];
  const float* biou = (const float*)d_in[6];
  const float* Wf   = (const float*)d_in[7];
  const float* Wfb  = (const float*)d_in[8];
  const float* Uf   = (const float*)d_in[9];
  const float* Ufb  = (const float*)d_in[10];
  const float* bfv  = (const float*)d_in[11];

  u16* Bpack = (u16*)d_ws;                              // 1 MB bf16 packed weights
  float* Bias = (float*)((char*)d_ws + (1 << 20));      // 4 KB combined bias
  u16* Apack = (u16*)((char*)d_ws + (2 << 20));         // 134.2 MB packed [x|hc] bf16

  const size_t need = (size_t)(2 << 20) + (size_t)NTOT * 512 * sizeof(u16);

  prep_bias<<<4, 256, 0, stream>>>(biou, Wfb, Ufb, bfv, Bias);

  if (ws_size >= need) {
    prep_w_frag<<<256, 256, 0, stream>>>(Wiou, Uiou, Wf, Uf, Bpack);
    prep_apack<<<32768, 256, 0, stream>>>(x, ch, ci, Apack);
    treelstm_main_v7<<<4096, 256, 0, stream>>>(Apack, Bpack, Bias, cc, ci, (float*)d_out);
  } else {
    prep_w_legacy<<<256, 256, 0, stream>>>(Wiou, Uiou, Wf, Uf, Bpack);
    dim3 grid(1024, 4);
    treelstm_main_f32<<<grid, 256, 0, stream>>>(x, ch, cc, ci, Bpack, Bias, (float*)d_out);
  }
}